// Round 5
// baseline (61.716 us; speedup 1.0000x reference)
//
#include <hip/hip_runtime.h>
#include <hip/hip_bf16.h>
#include <math.h>

#define BB 4
#define CC 64
#define HID 32
#define NN 4096
#define LOG2E 1.44269504088896f

typedef short sh2 __attribute__((ext_vector_type(2)));
typedef short sh4 __attribute__((ext_vector_type(4)));
typedef short sh8 __attribute__((ext_vector_type(8)));
typedef float f2v __attribute__((ext_vector_type(2)));
typedef float f4v __attribute__((ext_vector_type(4)));

#define MFMA32(A,B,C) __builtin_amdgcn_mfma_f32_16x16x32_bf16(A,B,C,0,0,0)

__device__ __forceinline__ short f2b(float f) {
    __hip_bfloat16 h = __float2bfloat16(f);
    union { __hip_bfloat16 hb; short s; } u; u.hb = h; return u.s;
}

// ---------------------------------------------------------------------------
// Kernel A: QKV projection -> bf16 Q[n][32] (pre-scaled by log2(e)),
// K[n][32], Vtp[32][n-permuted].  1024 thr, 4 waves/SIMD.
// V^T keys permuted within each 32-key block: pos(key) = 8*((key>>2)&3)
// + (key&3) + 4*(key>>4)  -> PV A-fragment is one contiguous 16B load.
// ---------------------------------------------------------------------------
__global__ __launch_bounds__(1024) void qkv_kernel(
    const float* __restrict__ x,
    const float* __restrict__ wq, const float* __restrict__ bq,
    const float* __restrict__ wk, const float* __restrict__ bk,
    const float* __restrict__ wv, const float* __restrict__ bv,
    short* __restrict__ Qw, short* __restrict__ Kw, short* __restrict__ Vtp)
{
    __shared__ float xs[64][80];
    __shared__ float ws[96][80];
    __shared__ float bs[96];

    const int t  = threadIdx.x;
    const int b  = blockIdx.x >> 6;
    const int n0 = (blockIdx.x & 63) << 6;

    {
        int c = t >> 4, j4 = (t & 15) << 2;
        *(f4v*)&xs[c][j4] = *(const f4v*)(x + ((size_t)(b*CC + c))*NN + n0 + j4);
    }
    #pragma unroll
    for (int kl = 0; kl < 2; ++kl) {
        int idx = t + 1024*kl;
        if (idx < 1536) {
            int r = idx >> 4, c4 = (idx & 15) << 2;
            const float* src = (r < 32) ? (wq + r*CC + c4)
                             : (r < 64) ? (wk + (r-32)*CC + c4)
                                        : (wv + (r-64)*CC + c4);
            *(f4v*)&ws[r][c4] = *(const f4v*)src;
        }
    }
    if (t < 96) bs[t] = (t < 32) ? bq[t] : (t < 64) ? bk[t-32] : bv[t-64];
    __syncthreads();

    const int hg = t & 31;
    const int j0 = (t >> 5) << 1;   // 2 spatial cols per thread

    float aq[2], ak[2], av[2];
    #pragma unroll
    for (int jj = 0; jj < 2; ++jj) { aq[jj]=bs[hg]; ak[jj]=bs[32+hg]; av[jj]=bs[64+hg]; }

    #pragma unroll
    for (int cs = 0; cs < 16; ++cs) {
        f4v wqv = *(f4v*)&ws[hg][cs*4];
        f4v wkv = *(f4v*)&ws[32+hg][cs*4];
        f4v wvv = *(f4v*)&ws[64+hg][cs*4];
        #pragma unroll
        for (int cc = 0; cc < 4; ++cc) {
            f2v xv = *(f2v*)&xs[cs*4+cc][j0];
            #pragma unroll
            for (int jj = 0; jj < 2; ++jj) {
                aq[jj] += wqv[cc]*xv[jj];
                ak[jj] += wkv[cc]*xv[jj];
                av[jj] += wvv[cc]*xv[jj];
            }
        }
    }

    const size_t nbase = (size_t)b*NN + n0 + j0;
    #pragma unroll
    for (int jj = 0; jj < 2; ++jj) {
        Qw[(nbase + jj)*HID + hg] = f2b(aq[jj] * LOG2E);  // exp2 trick
        Kw[(nbase + jj)*HID + hg] = f2b(ak[jj]);
    }
    const int w0  = j0 & 31;
    const int pos = 8*((w0 >> 2) & 3) + (w0 & 3) + 4*(w0 >> 4);
    sh2 vv; vv[0] = f2b(av[0]); vv[1] = f2b(av[1]);
    *(sh2*)(Vtp + ((size_t)b*HID + hg)*NN + n0 + (j0 & ~31) + pos) = vv;
}

// ---------------------------------------------------------------------------
// Kernel B: MFMA flash attention + projection + residual.
// 256 blocks x 1024 thr (16 waves = 4 q-subtiles x 4 key-quarters).
// Wave: 16 q x 1024 keys, 32 iters of 32 keys.  Depth-2 register prefetch,
// max-free softmax (exp2, Q pre-scaled), denominator in VALU.
// ---------------------------------------------------------------------------
__global__ __launch_bounds__(1024, 4) void attn_kernel(
    const short* __restrict__ Qw, const short* __restrict__ Kw,
    const short* __restrict__ Vtp, const float* __restrict__ x,
    const float* __restrict__ wp, const float* __restrict__ bp,
    float* __restrict__ out)
{
    __shared__ float zr[4][64][40];   // [quarter][q][d], pad 40
    __shared__ float lr[4][4][16];    // [quarter][S][qi]

    const int t    = threadIdx.x;
    const int b    = blockIdx.x >> 6;
    const int q0   = (blockIdx.x & 63) << 6;
    const int lane = t & 63;
    const int wave = t >> 6;
    const int S    = wave & 3;      // q-subtile (16 queries)
    const int kq   = wave >> 2;     // key quarter (1024 keys)
    const int g    = lane >> 4;
    const int qi   = lane & 15;

    const short* qbase = Qw + ((size_t)b*NN + q0 + S*16 + qi)*HID + 8*g;
    const sh8 qf = *(const sh8*)qbase;

    const short* kp = Kw  + ((size_t)b*NN  + kq*1024 + qi)*HID + 8*g;
    const short* vp = Vtp + ((size_t)b*HID + qi)*NN + kq*1024 + 8*g;

    const f4v zf = {0.f,0.f,0.f,0.f};
    f4v z0 = zf, z1 = zf;
    float lacc = 0.f;

    // depth-2 prefetch: A = iter it, B = iter it+1
    sh8 aA0 = *(const sh8*)kp;
    sh8 aA1 = *(const sh8*)(kp + 512);
    sh8 vA0 = *(const sh8*)vp;
    sh8 vA1 = *(const sh8*)(vp + 16*NN);
    sh8 aB0 = *(const sh8*)(kp + 1024);
    sh8 aB1 = *(const sh8*)(kp + 1536);
    sh8 vB0 = *(const sh8*)(vp + 32);
    sh8 vB1 = *(const sh8*)(vp + 32 + 16*NN);

#define STEP(A0,A1,V0,V1,NXT)                                            \
    {                                                                    \
        const short* kn = kp + (size_t)(NXT)*1024;                       \
        const short* vn = vp + (size_t)(NXT)*32;                         \
        sh8 na0 = *(const sh8*)kn;                                       \
        sh8 na1 = *(const sh8*)(kn + 512);                               \
        sh8 nv0 = *(const sh8*)vn;                                       \
        sh8 nv1 = *(const sh8*)(vn + 16*NN);                             \
        f4v s0 = MFMA32(A0, qf, zf);                                     \
        f4v s1 = MFMA32(A1, qf, zf);                                     \
        float e[8];                                                      \
        e[0]=__builtin_amdgcn_exp2f(s0[0]); e[1]=__builtin_amdgcn_exp2f(s0[1]); \
        e[2]=__builtin_amdgcn_exp2f(s0[2]); e[3]=__builtin_amdgcn_exp2f(s0[3]); \
        e[4]=__builtin_amdgcn_exp2f(s1[0]); e[5]=__builtin_amdgcn_exp2f(s1[1]); \
        e[6]=__builtin_amdgcn_exp2f(s1[2]); e[7]=__builtin_amdgcn_exp2f(s1[3]); \
        lacc += ((e[0]+e[1])+(e[2]+e[3])) + ((e[4]+e[5])+(e[6]+e[7]));   \
        sh8 p;                                                           \
        p[0]=f2b(e[0]); p[1]=f2b(e[1]); p[2]=f2b(e[2]); p[3]=f2b(e[3]);  \
        p[4]=f2b(e[4]); p[5]=f2b(e[5]); p[6]=f2b(e[6]); p[7]=f2b(e[7]);  \
        z0 = MFMA32(V0, p, z0);                                          \
        z1 = MFMA32(V1, p, z1);                                          \
        A0 = na0; A1 = na1; V0 = nv0; V1 = nv1;                          \
    }

    for (int it = 0; it < 32; it += 2) {
        const int nA = (it + 2 < 32) ? it + 2 : 31;
        const int nB = (it + 3 < 32) ? it + 3 : 31;
        STEP(aA0, aA1, vA0, vA1, nA);
        STEP(aB0, aB1, vB0, vB1, nB);
    }
#undef STEP

    lacc += __shfl_xor(lacc, 16, 64);
    lacc += __shfl_xor(lacc, 32, 64);

    *(f4v*)&zr[kq][S*16 + qi][4*g]      = z0;
    *(f4v*)&zr[kq][S*16 + qi][16 + 4*g] = z1;
    if (g == 0) lr[kq][S][qi] = lacc;
    __syncthreads();

    if (kq == 0) {
        const float lm = (lr[0][S][qi] + lr[1][S][qi])
                       + (lr[2][S][qi] + lr[3][S][qi]);
        f4v zm0 = zf, zm1 = zf;
        #pragma unroll
        for (int j = 0; j < 4; ++j) {
            f4v a = *(f4v*)&zr[j][S*16 + qi][4*g];
            f4v c = *(f4v*)&zr[j][S*16 + qi][16 + 4*g];
            zm0 += a; zm1 += c;
        }
        const float inv = 1.f / lm;
        sh8 pz;
        #pragma unroll
        for (int r = 0; r < 4; ++r) {
            pz[r]   = f2b(zm0[r]*inv);
            pz[4+r] = f2b(zm1[r]*inv);
        }
        const int qcol = q0 + S*16 + qi;
        #pragma unroll
        for (int ct = 0; ct < 4; ++ct) {
            const float* wrow = wp + (ct*16 + qi)*HID;
            f4v wa = *(const f4v*)(wrow + 4*g);
            f4v wb = *(const f4v*)(wrow + 16 + 4*g);
            sh8 af;
            #pragma unroll
            for (int i = 0; i < 4; ++i) { af[i] = f2b(wa[i]); af[4+i] = f2b(wb[i]); }
            f4v cacc;
            #pragma unroll
            for (int r = 0; r < 4; ++r) {
                int c = ct*16 + 4*g + r;
                cacc[r] = x[((size_t)(b*CC + c))*NN + qcol] + bp[c];
            }
            cacc = MFMA32(af, pz, cacc);
            #pragma unroll
            for (int r = 0; r < 4; ++r) {
                int c = ct*16 + 4*g + r;
                out[((size_t)(b*CC + c))*NN + qcol] = cacc[r];
            }
        }
    }
}

extern "C" void kernel_launch(void* const* d_in, const int* in_sizes, int n_in,
                              void* d_out, int out_size, void* d_ws, size_t ws_size,
                              hipStream_t stream) {
    const float* x  = (const float*)d_in[0];
    const float* wq = (const float*)d_in[1];
    const float* bq = (const float*)d_in[2];
    const float* wk = (const float*)d_in[3];
    const float* bk = (const float*)d_in[4];
    const float* wv = (const float*)d_in[5];
    const float* bv = (const float*)d_in[6];
    const float* wp = (const float*)d_in[7];
    const float* bp = (const float*)d_in[8];

    short* Qw  = (short*)d_ws;                       // bf16 [B][N][HID], pre-scaled log2(e)
    short* Kw  = Qw + (size_t)BB*NN*HID;             // bf16 [B][N][HID]
    short* Vtp = Kw + (size_t)BB*NN*HID;             // bf16 [B][HID][N-permuted]

    qkv_kernel<<<dim3(256), dim3(1024), 0, stream>>>(x, wq, bq, wk, bk, wv, bv, Qw, Kw, Vtp);
    attn_kernel<<<dim3(256), dim3(1024), 0, stream>>>(Qw, Kw, Vtp, x, wp, bp, (float*)d_out);
}